// Round 1
// baseline (39756.747 us; speedup 1.0000x reference)
//
#include <hip/hip_runtime.h>
#include <cmath>

// HM-LSTM forward, MI355X. Design (round 0):
//  - 1536 sequential stage kernels (t=0..511, layer=0..2) launched on `stream`;
//    stream order is the inter-stage sync (graph-capture safe).
//  - Each stage: 257 WGs x 512 threads. WG j (0..255) computes gate columns
//    {j, 256+j, 512+j, 768+j} for all 64 batch rows (weights amortized over
//    full batch), K split over 8 waves, LDS reduce, then 64 threads do the
//    elementwise cell update. WG 256 computes the z column in fp64 (the
//    binarization boundary s>0 must not flip vs the numpy fp32 reference).
//  - Weights pre-transposed once per call into d_ws as [col][k] (contiguous
//    per-column, wave-uniform scalar loads). State (h,c,z) transposed
//    [feature][batch] in d_ws, ping-ponged by timestep parity.
// ws usage: 8*262400 (WT) + 2*98304 (hT,cT) + 384 (z) floats = ~8.8 MB.

#define Hh   256
#define Bb   64
#define Tt   512
#define GC   1025
#define KW   256
#define MATF (GC * KW)          // 262400 floats per transposed matrix

struct Ptrs8 { const float* p[8]; };

__global__ __launch_bounds__(256) void transpose_w(Ptrs8 srcs, float* __restrict__ dst) {
    int k = blockIdx.x;                    // 0..255 (row of source = K index)
    int m = blockIdx.y;                    // 0..7   (matrix)
    const float* __restrict__ src = srcs.p[m];
    float* __restrict__ d = dst + (size_t)m * MATF;
#pragma unroll
    for (int c = 0; c < 5; ++c) {
        int col = c * 256 + threadIdx.x;
        if (col < GC) d[(size_t)col * KW + k] = src[(size_t)k * GC + col];
    }
}

struct StageP {
    const float* x;        // layer 0 bottom input (B,T,256)
    const float* Wb;       // transposed [col][k]
    const float* Wr;
    const float* Wt;       // null for layer 2
    const float* bias;     // (1025,)
    const float* h_rd;     // own h,  slot p   [k][b]
    const float* ht_rd;    // top h,  slot p   (null for layer 2)
    const float* hb_rd;    // below h, slot p^1 (null for layer 0 -> use x)
    const float* c_rd;     // slot p
    float*       c_wr;     // slot p^1
    const float* z_rd;     // own z (prev), slot p, (64,)
    const float* zb_rd;    // z below (this timestep), slot p^1 (null l==0 -> 1)
    float*       h_wr;     // slot p^1
    float*       z_wr;     // slot p^1
    float*       out_h;    // d_out h_all (B,T,768)
    float*       out_z;    // d_out z_all (B,T,3)
    int          t;
    int          layer;
};

__global__ __launch_bounds__(512) void stage_kernel(StageP P) {
    __shared__ float  sred[8][4][64];
    __shared__ double zred[8][3][64];

    const int tid  = threadIdx.x;
    const int lane = tid & 63;    // batch row
    const int wv   = tid >> 6;    // 0..7, K chunk
    const int wg   = blockIdx.x;
    const int t = P.t, l = P.layer;
    const int k0 = wv * 32;

    if (wg < 256) {
        const int j = wg;
        const float zb = (l == 0) ? 1.0f : P.zb_rd[lane];
        const float zo = P.z_rd[lane];
        const bool hasT = (l < 2);

        const float* __restrict__ wb0 = P.Wb + (size_t)(0 * Hh + j) * KW;
        const float* __restrict__ wb1 = P.Wb + (size_t)(1 * Hh + j) * KW;
        const float* __restrict__ wb2 = P.Wb + (size_t)(2 * Hh + j) * KW;
        const float* __restrict__ wb3 = P.Wb + (size_t)(3 * Hh + j) * KW;
        const float* __restrict__ wr0 = P.Wr + (size_t)(0 * Hh + j) * KW;
        const float* __restrict__ wr1 = P.Wr + (size_t)(1 * Hh + j) * KW;
        const float* __restrict__ wr2 = P.Wr + (size_t)(2 * Hh + j) * KW;
        const float* __restrict__ wr3 = P.Wr + (size_t)(3 * Hh + j) * KW;
        const float* __restrict__ wt0 = hasT ? P.Wt + (size_t)(0 * Hh + j) * KW : nullptr;
        const float* __restrict__ wt1 = hasT ? P.Wt + (size_t)(1 * Hh + j) * KW : nullptr;
        const float* __restrict__ wt2 = hasT ? P.Wt + (size_t)(2 * Hh + j) * KW : nullptr;
        const float* __restrict__ wt3 = hasT ? P.Wt + (size_t)(3 * Hh + j) * KW : nullptr;
        const float* __restrict__ xrow = (l == 0) ? P.x + ((size_t)lane * Tt + t) * Hh : nullptr;

        float a0 = 0.f, a1 = 0.f, a2 = 0.f, a3 = 0.f;
#pragma unroll 8
        for (int k = k0; k < k0 + 32; ++k) {
            float hbv = (l == 0) ? xrow[k] : P.hb_rd[k * 64 + lane];
            float hv  = P.h_rd[k * 64 + lane];
            float hbz = zb * hbv;
            a0 += wb0[k] * hbz + wr0[k] * hv;
            a1 += wb1[k] * hbz + wr1[k] * hv;
            a2 += wb2[k] * hbz + wr2[k] * hv;
            a3 += wb3[k] * hbz + wr3[k] * hv;
            if (hasT) {
                float htz = zo * P.ht_rd[k * 64 + lane];
                a0 += wt0[k] * htz;
                a1 += wt1[k] * htz;
                a2 += wt2[k] * htz;
                a3 += wt3[k] * htz;
            }
        }
        sred[wv][0][lane] = a0; sred[wv][1][lane] = a1;
        sred[wv][2][lane] = a2; sred[wv][3][lane] = a3;
        __syncthreads();
        if (tid < 64) {
            const int b = tid;
            float s0 = P.bias[0 * Hh + j];
            float s1 = P.bias[1 * Hh + j];
            float s2 = P.bias[2 * Hh + j];
            float s3 = P.bias[3 * Hh + j];
#pragma unroll
            for (int v = 0; v < 8; ++v) {
                s0 += sred[v][0][b]; s1 += sred[v][1][b];
                s2 += sred[v][2][b]; s3 += sred[v][3][b];
            }
            float f = 1.0f / (1.0f + expf(-s0));
            float i = 1.0f / (1.0f + expf(-s1));
            float o = 1.0f / (1.0f + expf(-s2));
            float g = tanhf(s3);
            float zb_ = (l == 0) ? 1.0f : P.zb_rd[b];
            float zo_ = P.z_rd[b];
            float c    = P.c_rd[j * 64 + b];
            float hold = P.h_rd[j * 64 + b];
            float ig   = i * g;
            float cupd = f * c + ig;
            // z, zb in {0,1} exactly -> selects are bit-identical to the
            // reference's z*(..) + (1-z)*(..) arithmetic.
            float cnew = (zo_ != 0.0f) ? ig : ((zb_ != 0.0f) ? cupd : c);
            float hnew = (zo_ == 0.0f && zb_ == 0.0f) ? hold : (o * tanhf(cnew));
            P.c_wr[j * 64 + b] = cnew;
            P.h_wr[j * 64 + b] = hnew;
            P.out_h[((size_t)b * Tt + t) * (3 * Hh) + l * Hh + j] = hnew;
        }
    } else {
        // z column (col 1024), fp64 accumulation to keep the s>0 binarization
        // boundary aligned with the fp32 numpy reference.
        const float* __restrict__ wbz = P.Wb + (size_t)1024 * KW;
        const float* __restrict__ wrz = P.Wr + (size_t)1024 * KW;
        const float* __restrict__ wtz = (l < 2) ? P.Wt + (size_t)1024 * KW : nullptr;
        const float* __restrict__ xrow = (l == 0) ? P.x + ((size_t)lane * Tt + t) * Hh : nullptr;
        double aB = 0.0, aR = 0.0, aT = 0.0;
#pragma unroll 4
        for (int k = k0; k < k0 + 32; ++k) {
            float hbv = (l == 0) ? xrow[k] : P.hb_rd[k * 64 + lane];
            aB += (double)wbz[k] * (double)hbv;
            aR += (double)wrz[k] * (double)P.h_rd[k * 64 + lane];
            if (l < 2) aT += (double)wtz[k] * (double)P.ht_rd[k * 64 + lane];
        }
        zred[wv][0][lane] = aB; zred[wv][1][lane] = aR; zred[wv][2][lane] = aT;
        __syncthreads();
        if (tid < 64) {
            const int b = tid;
            double sB = 0.0, sR = 0.0, sT = 0.0;
#pragma unroll
            for (int v = 0; v < 8; ++v) {
                sB += zred[v][0][b]; sR += zred[v][1][b]; sT += zred[v][2][b];
            }
            double zb_ = (l == 0) ? 1.0 : (double)P.zb_rd[b];
            double zo_ = (double)P.z_rd[b];
            double s = (double)P.bias[1024] + zb_ * sB + sR + zo_ * sT;
            // round(clip((s+1)/2,0,1)) with round-half-even == (s > 0)
            float znew = (s > 0.0) ? 1.0f : 0.0f;
            P.z_wr[b] = znew;
            P.out_z[((size_t)b * Tt + t) * 3 + l] = znew;
        }
    }
}

extern "C" void kernel_launch(void* const* d_in, const int* in_sizes, int n_in,
                              void* d_out, int out_size, void* d_ws, size_t ws_size,
                              hipStream_t stream) {
    (void)in_sizes; (void)n_in; (void)out_size; (void)ws_size;

    const float* x = (const float*)d_in[0];
    // dict order: x, Wb0,Wr0,Wt0,b0, Wb1,Wr1,Wt1,b1, Wb2,Wr2,Wt2,b2
    const float* biases[3] = { (const float*)d_in[4], (const float*)d_in[8], (const float*)d_in[12] };

    float* wsf = (float*)d_ws;
    float* WT  = wsf;                               // 8 * 262400 floats
    float* hT  = WT + 8 * (size_t)MATF;             // [2][3][256][64]
    float* cT  = hT + 2 * 3 * Hh * Bb;              // [2][3][256][64]
    float* zS  = cT + 2 * 3 * Hh * Bb;              // [2][3][64]

    // Zero the recurrent state each call (ws is not re-poisoned between replays,
    // and t=0 reads parity-0 state as the zero initial condition).
    size_t stateBytes = (size_t)(2 * 3 * Hh * Bb * 2 + 2 * 3 * Bb) * sizeof(float);
    hipMemsetAsync(hT, 0, stateBytes, stream);

    Ptrs8 ps;
    const int mi[8] = { 1, 2, 3, 5, 6, 7, 9, 10 };  // Wb0,Wr0,Wt0,Wb1,Wr1,Wt1,Wb2,Wr2
    for (int i = 0; i < 8; ++i) ps.p[i] = (const float*)d_in[mi[i]];
    transpose_w<<<dim3(256, 8), 256, 0, stream>>>(ps, WT);

    float* out_h = (float*)d_out;
    float* out_z = out_h + (size_t)Bb * Tt * (3 * Hh);

    const int wmb[3] = { 0, 3, 6 };
    const int wmr[3] = { 1, 4, 7 };
    const int wmt[3] = { 2, 5, -1 };

    auto hS = [&](int pp, int ll) { return hT + ((size_t)pp * 3 + ll) * (Hh * Bb); };
    auto cS = [&](int pp, int ll) { return cT + ((size_t)pp * 3 + ll) * (Hh * Bb); };
    auto zSl = [&](int pp, int ll) { return zS + ((size_t)pp * 3 + ll) * Bb; };

    for (int t = 0; t < Tt; ++t) {
        int p = t & 1;
        for (int l = 0; l < 3; ++l) {
            StageP P;
            P.x    = (l == 0) ? x : nullptr;
            P.Wb   = WT + (size_t)wmb[l] * MATF;
            P.Wr   = WT + (size_t)wmr[l] * MATF;
            P.Wt   = (l < 2) ? WT + (size_t)wmt[l] * MATF : nullptr;
            P.bias = biases[l];
            P.h_rd  = hS(p, l);
            P.ht_rd = (l < 2) ? hS(p, l + 1) : nullptr;
            P.hb_rd = (l > 0) ? hS(p ^ 1, l - 1) : nullptr;
            P.c_rd  = cS(p, l);
            P.c_wr  = cS(p ^ 1, l);
            P.z_rd  = zSl(p, l);
            P.zb_rd = (l > 0) ? zSl(p ^ 1, l - 1) : nullptr;
            P.h_wr  = hS(p ^ 1, l);
            P.z_wr  = zSl(p ^ 1, l);
            P.out_h = out_h;
            P.out_z = out_z;
            P.t     = t;
            P.layer = l;
            stage_kernel<<<257, 512, 0, stream>>>(P);
        }
    }
}